// Round 3
// baseline (2283.595 us; speedup 1.0000x reference)
//
#include <hip/hip_runtime.h>
#include <hip/hip_bf16.h>

// W8A16 linear: M = B*S = 8192, K = IN = 4096, N = OUT = 16384.
// out[m][n] = (sum_k x[m][k]*w[n][k]) * scales[n] + bias[n]
//
// Round-3 dtype model (from round-1/2 forensics: absmax = bf16((4/3)*2^72),
// the unique signature of fp16-promoted-f32 data read as bf16 pairs):
//   x:      float32 [M][K]   (fp16 promoted; low 13 mantissa bits zero)
//   w:      int32   [N][K]   (int8-range values)
//   scales: float32 [N]
//   bias:   float32 [N]
//   out:    float32 [M][N]   (header: output "bfloat16 -> bf16*, ELSE float*")
#define M_DIM 8192
#define N_DIM 16384
#define K_DIM 4096

typedef __attribute__((ext_vector_type(8))) short          bf16x8; // MFMA A/B frag
typedef __attribute__((ext_vector_type(4))) float          f32x4;
typedef __attribute__((ext_vector_type(4))) int            i32x4;
typedef __attribute__((ext_vector_type(8))) unsigned short u16x8;

__device__ __forceinline__ unsigned short f2bf_rne(float f) {
    unsigned int u = __builtin_bit_cast(unsigned int, f);
    return (unsigned short)((u + 0x7fffu + ((u >> 16) & 1u)) >> 16);
}
// int8-range -> f32 -> bf16 truncation is exact (low mantissa bits are zero).
__device__ __forceinline__ unsigned short i2bf(int v) {
    return (unsigned short)(__builtin_bit_cast(unsigned int, (float)v) >> 16);
}

// Async global->LDS, 16B/lane; LDS dest = wave-uniform base + lane*16 (m97).
__device__ __forceinline__ void gload_lds16(const void* g, void* l) {
    __builtin_amdgcn_global_load_lds(
        (const __attribute__((address_space(1))) unsigned int*)g,
        (__attribute__((address_space(3))) unsigned int*)l, 16, 0, 0);
}

// ---------------- converters (PRE path) ----------------
__global__ __launch_bounds__(256) void convert_x_kernel(const float* __restrict__ xi,
                                                        unsigned short* __restrict__ xo) {
    const int idx = (blockIdx.x * 256 + threadIdx.x) * 8; // < 33,554,432
    f32x4 a = *(const f32x4*)(xi + idx);
    f32x4 b = *(const f32x4*)(xi + idx + 4);
    u16x8 o;
    o[0] = f2bf_rne(a[0]); o[1] = f2bf_rne(a[1]); o[2] = f2bf_rne(a[2]); o[3] = f2bf_rne(a[3]);
    o[4] = f2bf_rne(b[0]); o[5] = f2bf_rne(b[1]); o[6] = f2bf_rne(b[2]); o[7] = f2bf_rne(b[3]);
    *(u16x8*)(xo + idx) = o;
}

__global__ __launch_bounds__(256) void convert_w_kernel(const int* __restrict__ wi,
                                                        unsigned short* __restrict__ wo) {
    const int idx = (blockIdx.x * 256 + threadIdx.x) * 8; // < 67,108,864
    i32x4 a = *(const i32x4*)(wi + idx);
    i32x4 b = *(const i32x4*)(wi + idx + 4);
    u16x8 o;
    o[0] = i2bf(a[0]); o[1] = i2bf(a[1]); o[2] = i2bf(a[2]); o[3] = i2bf(a[3]);
    o[4] = i2bf(b[0]); o[5] = i2bf(b[1]); o[6] = i2bf(b[2]); o[7] = i2bf(b[3]);
    *(u16x8*)(wo + idx) = o;
}

// ---------------- shared GEMM pieces ----------------
// 8x8 supertile swizzle, bijection over 64x128 blocks of 128x128 tiles.
__device__ __forceinline__ void tile_origin(int bid, int& m0, int& n0) {
    const int ls = bid & 63, st = bid >> 6;
    m0 = ((st & 7) * 8 + (ls & 7)) * 128;
    n0 = ((st >> 3) * 8 + (ls >> 3)) * 128;
}

__device__ __forceinline__ void epilogue(const f32x4 acc[4][4], int m0, int n0,
                                         int lm, int quad, int wr, int wc,
                                         const float* __restrict__ scales,
                                         const float* __restrict__ bias,
                                         float* __restrict__ C) {
    // C/D layout: col(n) = lane&15, row(m) = quad*4 + reg  [m89/m91 verified]
#pragma unroll
    for (int j = 0; j < 4; ++j) {
        const int n  = n0 + wc * 64 + j * 16 + lm;
        const float sc = scales[n];
        const float bv = bias[n];
#pragma unroll
        for (int i = 0; i < 4; ++i) {
            const int mb = m0 + wr * 64 + i * 16 + quad * 4;
#pragma unroll
            for (int r = 0; r < 4; ++r)
                C[(long)(mb + r) * N_DIM + n] = acc[i][j][r] * sc + bv;
        }
    }
}

// ---------------- PRE path GEMM: both operands already bf16 in ws ----------
__global__ __launch_bounds__(256) void gemm_pre(
    const unsigned short* __restrict__ A,  // bf16 [M][K]
    const unsigned short* __restrict__ W,  // bf16 [N][K]
    const float* __restrict__ scales, const float* __restrict__ bias,
    float* __restrict__ C)
{
    constexpr int BK = 32;
    __shared__ __align__(16) unsigned short As[128 * BK];
    __shared__ __align__(16) unsigned short Bs[128 * BK];

    const int tid = threadIdx.x;
    int m0, n0; tile_origin(blockIdx.x, m0, n0);
    const int lane = tid & 63, lm = lane & 15, quad = lane >> 4;
    const int wr = (tid >> 7) & 1, wc = (tid >> 6) & 1;

    // staging chunk map: chunk c -> row c>>2, col (c&3)*8; LDS idx = c*8
    const int rA = tid >> 2, cA = (tid & 3) * 8;
    const unsigned short* gA0 = A + (long)(m0 + rA) * K_DIM + cA;
    const unsigned short* gA1 = gA0 + (long)64 * K_DIM;
    const unsigned short* gB0 = W + (long)(n0 + rA) * K_DIM + cA;
    const unsigned short* gB1 = gB0 + (long)64 * K_DIM;
    unsigned short* lA0 = As + tid * 8;
    unsigned short* lA1 = As + (tid + 256) * 8;
    unsigned short* lB0 = Bs + tid * 8;
    unsigned short* lB1 = Bs + (tid + 256) * 8;

    f32x4 acc[4][4] = {};

    for (int k0 = 0; k0 < K_DIM; k0 += BK) {
        gload_lds16(gA0 + k0, lA0);
        gload_lds16(gA1 + k0, lA1);
        gload_lds16(gB0 + k0, lB0);
        gload_lds16(gB1 + k0, lB1);
        __syncthreads(); // drain global_load_lds

        bf16x8 af[4], bf[4];
#pragma unroll
        for (int i = 0; i < 4; ++i)
            af[i] = *(const bf16x8*)&As[(wr * 64 + i * 16 + lm) * BK + quad * 8];
#pragma unroll
        for (int j = 0; j < 4; ++j)
            bf[j] = *(const bf16x8*)&Bs[(wc * 64 + j * 16 + lm) * BK + quad * 8];
#pragma unroll
        for (int i = 0; i < 4; ++i)
#pragma unroll
            for (int j = 0; j < 4; ++j)
                acc[i][j] = __builtin_amdgcn_mfma_f32_16x16x32_bf16(af[i], bf[j], acc[i][j], 0, 0, 0);
        __syncthreads(); // all reads done before next staging
    }
    epilogue(acc, m0, n0, lm, quad, wr, wc, scales, bias, C);
}

// ---------------- fallback GEMM: fused convert, no workspace -------------
__global__ __launch_bounds__(256) void gemm_fused(
    const float* __restrict__ X,   // f32 [M][K]
    const int* __restrict__ W,     // int32 [N][K]
    const float* __restrict__ scales, const float* __restrict__ bias,
    float* __restrict__ C)
{
    constexpr int BK = 32;
    __shared__ __align__(16) unsigned short As[128 * BK];
    __shared__ __align__(16) unsigned short Bs[128 * BK];

    const int tid = threadIdx.x;
    int m0, n0; tile_origin(blockIdx.x, m0, n0);
    const int lane = tid & 63, lm = lane & 15, quad = lane >> 4;
    const int wr = (tid >> 7) & 1, wc = (tid >> 6) & 1;

    const int rA = tid >> 2, cA = (tid & 3) * 8;
    const float* gA0 = X + (long)(m0 + rA) * K_DIM + cA;
    const float* gA1 = gA0 + (long)64 * K_DIM;
    const int rB = tid >> 1, hB = (tid & 1) * 16;
    const int* gB = W + (long)(n0 + rB) * K_DIM + hB;

    f32x4 acc[4][4] = {};

    for (int k0 = 0; k0 < K_DIM; k0 += BK) {
        f32x4 xa0 = *(const f32x4*)(gA0 + k0), xa1 = *(const f32x4*)(gA0 + k0 + 4);
        f32x4 xb0 = *(const f32x4*)(gA1 + k0), xb1 = *(const f32x4*)(gA1 + k0 + 4);
        i32x4 w0 = *(const i32x4*)(gB + k0),      w1 = *(const i32x4*)(gB + k0 + 4);
        i32x4 w2 = *(const i32x4*)(gB + k0 + 8),  w3 = *(const i32x4*)(gB + k0 + 12);

        __syncthreads(); // previous iteration's reads complete

        u16x8 oa, ob, wb0, wb1;
        oa[0]=f2bf_rne(xa0[0]); oa[1]=f2bf_rne(xa0[1]); oa[2]=f2bf_rne(xa0[2]); oa[3]=f2bf_rne(xa0[3]);
        oa[4]=f2bf_rne(xa1[0]); oa[5]=f2bf_rne(xa1[1]); oa[6]=f2bf_rne(xa1[2]); oa[7]=f2bf_rne(xa1[3]);
        ob[0]=f2bf_rne(xb0[0]); ob[1]=f2bf_rne(xb0[1]); ob[2]=f2bf_rne(xb0[2]); ob[3]=f2bf_rne(xb0[3]);
        ob[4]=f2bf_rne(xb1[0]); ob[5]=f2bf_rne(xb1[1]); ob[6]=f2bf_rne(xb1[2]); ob[7]=f2bf_rne(xb1[3]);
        *(u16x8*)&As[rA * BK + cA]        = oa;
        *(u16x8*)&As[(rA + 64) * BK + cA] = ob;
        wb0[0]=i2bf(w0[0]); wb0[1]=i2bf(w0[1]); wb0[2]=i2bf(w0[2]); wb0[3]=i2bf(w0[3]);
        wb0[4]=i2bf(w1[0]); wb0[5]=i2bf(w1[1]); wb0[6]=i2bf(w1[2]); wb0[7]=i2bf(w1[3]);
        wb1[0]=i2bf(w2[0]); wb1[1]=i2bf(w2[1]); wb1[2]=i2bf(w2[2]); wb1[3]=i2bf(w2[3]);
        wb1[4]=i2bf(w3[0]); wb1[5]=i2bf(w3[1]); wb1[6]=i2bf(w3[2]); wb1[7]=i2bf(w3[3]);
        *(u16x8*)&Bs[rB * BK + hB]     = wb0;
        *(u16x8*)&Bs[rB * BK + hB + 8] = wb1;

        __syncthreads(); // tile visible

        bf16x8 af[4], bf[4];
#pragma unroll
        for (int i = 0; i < 4; ++i)
            af[i] = *(const bf16x8*)&As[(wr * 64 + i * 16 + lm) * BK + quad * 8];
#pragma unroll
        for (int j = 0; j < 4; ++j)
            bf[j] = *(const bf16x8*)&Bs[(wc * 64 + j * 16 + lm) * BK + quad * 8];
#pragma unroll
        for (int i = 0; i < 4; ++i)
#pragma unroll
            for (int j = 0; j < 4; ++j)
                acc[i][j] = __builtin_amdgcn_mfma_f32_16x16x32_bf16(af[i], bf[j], acc[i][j], 0, 0, 0);
    }
    epilogue(acc, m0, n0, lm, quad, wr, wc, scales, bias, C);
}

extern "C" void kernel_launch(void* const* d_in, const int* in_sizes, int n_in,
                              void* d_out, int out_size, void* d_ws, size_t ws_size,
                              hipStream_t stream) {
    const float* x  = (const float*)d_in[0]; // f32 [B,S,IN] (fp16-promoted)
    const int*   wq = (const int*)d_in[1];   // int32 [OUT,IN]
    const float* sc = (const float*)d_in[2]; // f32 [OUT]
    const float* bi = (const float*)d_in[3]; // f32 [OUT]
    float*       out = (float*)d_out;        // f32 [M][OUT]

    const size_t xbf_bytes = (size_t)M_DIM * K_DIM * 2;   // 67,108,864
    const size_t wbf_bytes = (size_t)N_DIM * K_DIM * 2;   // 134,217,728
    const int gemm_blocks = (M_DIM / 128) * (N_DIM / 128); // 8192

    if (ws_size >= xbf_bytes + wbf_bytes) {
        unsigned short* xbf = (unsigned short*)d_ws;
        unsigned short* wbf = (unsigned short*)((char*)d_ws + xbf_bytes);
        convert_x_kernel<<<(M_DIM * K_DIM) / 2048, 256, 0, stream>>>(x, xbf);
        convert_w_kernel<<<(N_DIM * K_DIM) / 2048, 256, 0, stream>>>(wq, wbf);
        gemm_pre<<<gemm_blocks, 256, 0, stream>>>(xbf, wbf, sc, bi, out);
    } else {
        gemm_fused<<<gemm_blocks, 256, 0, stream>>>(x, wq, sc, bi, out);
    }
}